// Round 9
// baseline (380.514 us; speedup 1.0000x reference)
//
#include <hip/hip_runtime.h>
#include <hip/hip_bf16.h>
#include <math.h>

#define B_ 2
#define T_ 2048
#define D_ 2048
#define H_ 16
#define DH_ 128
#define SEM_ 1024
#define GEO_ 1024
#define NPROJ 6144   // 4*1024 (q/k sem/geo) + 2048 (v)

typedef unsigned short ushort_t;
typedef short bf16x8 __attribute__((ext_vector_type(8)));
typedef float f32x4 __attribute__((ext_vector_type(4)));
typedef unsigned short us4 __attribute__((ext_vector_type(4)));
typedef unsigned short us2 __attribute__((ext_vector_type(2)));

static __device__ inline ushort_t f2b(float x) {
    __hip_bfloat16 h = __float2bfloat16(x);
    return *reinterpret_cast<ushort_t*>(&h);
}
static __device__ inline float b2f(ushort_t u) {
    union { unsigned int i; float f; } v; v.i = ((unsigned int)u) << 16; return v.f;
}
static __device__ inline void gload_lds16(const ushort_t* g, ushort_t* l) {
    __builtin_amdgcn_global_load_lds(
        (const __attribute__((address_space(1))) void*)g,
        (__attribute__((address_space(3))) void*)l, 16, 0, 0);
}

#define BARS()  { asm volatile("" ::: "memory"); __builtin_amdgcn_s_barrier(); asm volatile("" ::: "memory"); }
#define WL0()   asm volatile("s_waitcnt lgkmcnt(0)" ::: "memory")
#define WV6()   asm volatile("s_waitcnt vmcnt(6)" ::: "memory")
#define WV4()   asm volatile("s_waitcnt vmcnt(4)" ::: "memory")
#define WV0()   asm volatile("s_waitcnt vmcnt(0)" ::: "memory")

// ---------------------------------------------------------------------------
// x fp32 -> bf16, 8 elems/thread
// ---------------------------------------------------------------------------
__global__ __launch_bounds__(256) void convert_x(
    const float* __restrict__ x, ushort_t* __restrict__ xh)
{
    size_t i = ((size_t)blockIdx.x * 256 + threadIdx.x) * 8;
    float4 a = *(const float4*)&x[i];
    float4 b = *(const float4*)&x[i + 4];
    bf16x8 o;
    o[0] = (short)f2b(a.x); o[1] = (short)f2b(a.y);
    o[2] = (short)f2b(a.z); o[3] = (short)f2b(a.w);
    o[4] = (short)f2b(b.x); o[5] = (short)f2b(b.y);
    o[6] = (short)f2b(b.z); o[7] = (short)f2b(b.w);
    *(bf16x8*)&xh[i] = o;
}

// ---------------------------------------------------------------------------
// All 6 weight transposes in one launch. z selects the weight.
// W[K=2048][N] fp32 -> dst[N][2048] bf16.  64x64 tiles, float2 reads,
// ushort2 writes.
// ---------------------------------------------------------------------------
__global__ __launch_bounds__(256) void transpose_all(
    const float* __restrict__ W0, const float* __restrict__ W1,
    const float* __restrict__ W2, const float* __restrict__ W3,
    const float* __restrict__ W4, const float* __restrict__ W5,
    ushort_t* __restrict__ Wt_all, ushort_t* __restrict__ WoT)
{
    const int z = blockIdx.z;
    const float* W;
    ushort_t* dst;
    int N;
    switch (z) {
        case 0: W = W0; dst = Wt_all;                          N = 1024; break;
        case 1: W = W1; dst = Wt_all + (size_t)1024 * 2048;    N = 1024; break;
        case 2: W = W2; dst = Wt_all + (size_t)2048 * 2048;    N = 1024; break;
        case 3: W = W3; dst = Wt_all + (size_t)3072 * 2048;    N = 1024; break;
        case 4: W = W4; dst = Wt_all + (size_t)4096 * 2048;    N = 2048; break;
        default: W = W5; dst = WoT;                            N = 2048; break;
    }
    const int n0 = blockIdx.x * 64;
    if (n0 >= N) return;
    const int k0 = blockIdx.y * 64;

    __shared__ float tile[64][66];
    const int c2 = (threadIdx.x & 31) * 2;   // n-col pair
    const int r  = threadIdx.x >> 5;         // 0..7
#pragma unroll
    for (int rr = 0; rr < 64; rr += 8) {
        float2 v = *(const float2*)&W[(size_t)(k0 + r + rr) * N + n0 + c2];
        tile[r + rr][c2]     = v.x;
        tile[r + rr][c2 + 1] = v.y;
    }
    __syncthreads();
    const int kc = (threadIdx.x & 31) * 2;   // k-col pair
#pragma unroll
    for (int rr = 0; rr < 64; rr += 8) {
        int nrow = r + rr;
        us2 o;
        o[0] = f2b(tile[kc][nrow]);
        o[1] = f2b(tile[kc + 1][nrow]);
        *(us2*)&dst[(size_t)(n0 + nrow) * 2048 + k0 + kc] = o;
    }
}

// ---------------------------------------------------------------------------
// Projection GEMM — round-9: BM=128 x BN=256, BK=64, 768 blocks = exact 3
// dispatch rounds.  TRIPLE-buffered LDS (144 KiB) fixes round-8's race:
// stage(t+2) -> buf[(t+2)%3] == buf[(t-1)%3] (tile t-1's buffer), whose
// reads ALL completed (every wave's WL0) before iteration t-1's final
// barrier — the proven staging invariant.  vmcnt ledger: 6 loads/tile,
// 2 tiles in flight; WV6 in P2 guarantees stage(t+1) landed while leaving
// stage(t+2) flying; WV0 only at t>=30.  T2 3-bit XOR swizzle + T5.
// Per-acc-element K order unchanged (bit-identical numerics to r0-r7).
// ---------------------------------------------------------------------------
#define PLDA(par, i4, kk) \
    (*(const bf16x8*)&smA[(par)*8192 + aoff + (i4)*1024 + ((kk) ? ca1 : ca0)])
#define PLDB(par, j, kk) \
    (*(const bf16x8*)&smB[(par)*16384 + boff + (j)*1024 + ((kk) ? ca1 : ca0)])

// read one kk-slice (4 A frags + 4 B frags) into slots [off, off+4)
#define PREAD_SET(par, kk, off) \
    aF[(off)+0]=PLDA(par,0,kk); aF[(off)+1]=PLDA(par,1,kk); \
    aF[(off)+2]=PLDA(par,2,kk); aF[(off)+3]=PLDA(par,3,kk); \
    bF[(off)+0]=PLDB(par,0,kk); bF[(off)+1]=PLDB(par,1,kk); \
    bF[(off)+2]=PLDB(par,2,kk); bF[(off)+3]=PLDB(par,3,kk);

#define PMM(off) do { \
    _Pragma("unroll") \
    for (int i = 0; i < 4; ++i) { \
        acc[i][0] = __builtin_amdgcn_mfma_f32_16x16x32_bf16(aF[(off)+i], bF[(off)+0], acc[i][0], 0, 0, 0); \
        acc[i][1] = __builtin_amdgcn_mfma_f32_16x16x32_bf16(aF[(off)+i], bF[(off)+1], acc[i][1], 0, 0, 0); \
        acc[i][2] = __builtin_amdgcn_mfma_f32_16x16x32_bf16(aF[(off)+i], bF[(off)+2], acc[i][2], 0, 0, 0); \
        acc[i][3] = __builtin_amdgcn_mfma_f32_16x16x32_bf16(aF[(off)+i], bF[(off)+3], acc[i][3], 0, 0, 0); \
    } \
} while(0)

#define PSTAGE_A(kt, par) do { \
    const ushort_t* _s = gAbase + (size_t)(kt) * 64 + stgoff; \
    ushort_t* _d = smA + (par)*8192 + wid*512; \
    gload_lds16(_s, _d); \
    gload_lds16(_s + (size_t)64*2048, _d + 4096); \
} while(0)

#define PSTAGE_B(kt, par) do { \
    const ushort_t* _s = gBbase + (size_t)(kt) * 64 + stgoff; \
    ushort_t* _d = smB + (par)*16384 + wid*512; \
    gload_lds16(_s, _d); \
    gload_lds16(_s + (size_t)64*2048,  _d + 4096); \
    gload_lds16(_s + (size_t)128*2048, _d + 8192); \
    gload_lds16(_s + (size_t)192*2048, _d + 12288); \
} while(0)

__global__ __launch_bounds__(512, 2) void gemm_proj(
    const ushort_t* __restrict__ A, const ushort_t* __restrict__ Bt,
    const float* __restrict__ gate_logit, const int* __restrict__ pos_off,
    ushort_t* __restrict__ Qh, ushort_t* __restrict__ Kh,
    ushort_t* __restrict__ Vt)
{
    extern __shared__ __align__(16) ushort_t smdyn[];
    ushort_t* smA = smdyn;              // [3 buf][128][64]  48 KiB
    ushort_t* smB = smdyn + 24576;      // [3 buf][256][64]  96 KiB

    const int tid  = threadIdx.x;
    const int wid  = tid >> 6, lane = tid & 63;
    const int ln16 = lane & 15, g = lane >> 4;
    const int wm = wid & 1, wn = wid >> 1;          // wn 0..3
    const int m0 = blockIdx.y * 128, n0 = blockIdx.x * 256;

    // staging: wave stages 8-row slabs; global source granule pre-swizzled
    // by (row&7) so the linear global_load_lds write realizes the 3-bit XOR.
    const int srow = wid * 8 + (lane >> 3);
    const int scol = ((lane & 7) ^ (lane >> 3)) * 8;
    const size_t stgoff = (size_t)srow * 2048 + scol;
    const ushort_t* gAbase = A  + (size_t)m0 * 2048;
    const ushort_t* gBbase = Bt + (size_t)n0 * 2048;

    // ds-read swizzled granule: (g+4kk) ^ (ln16&7)
    const int cg0 = ln16 & 7;
    const int ca0 = ((g + 0) ^ cg0) * 8;
    const int ca1 = ((g + 4) ^ cg0) * 8;
    const int aoff = wm * 4096 + ln16 * 64;
    const int boff = wn * 4096 + ln16 * 64;

    f32x4 acc[4][4];
#pragma unroll
    for (int i = 0; i < 4; ++i)
#pragma unroll
        for (int j = 0; j < 4; ++j) acc[i][j] = (f32x4){0.f, 0.f, 0.f, 0.f};
    bf16x8 aF[8], bF[8];

    // prologue: tile0 -> buf0, tile1 -> buf1 (6 loads each)
    PSTAGE_A(0, 0); PSTAGE_B(0, 0);
    PSTAGE_A(1, 1); PSTAGE_B(1, 1);
    WV6();                              // tile0 landed (6 of tile1 in flight)
    BARS();
    PREAD_SET(0, 0, 0);                 // tile0 kk0

    int par = 0, pn1 = 1, pn2 = 2;
#pragma unroll 1
    for (int t = 0; t < 32; ++t) {
        const int t2 = t + 2;
        // P1 (kk=0 of tile t)
        if (t2 < 32) { PSTAGE_A(t2, pn2); PSTAGE_B(t2, pn2); }
        BARS(); WL0();
        __builtin_amdgcn_s_setprio(1); PMM(0); __builtin_amdgcn_s_setprio(0);
        PREAD_SET(par, 1, 4);           // kk1 reads of tile t
        BARS();
        // P2 (kk=1 of tile t)
        if (t < 30) { WV6(); } else { WV0(); }   // stage(t+1) landed
        BARS(); WL0();
        __builtin_amdgcn_s_setprio(1); PMM(4); __builtin_amdgcn_s_setprio(0);
        PREAD_SET(pn1, 0, 0);           // tile t+1 kk0 (buffer landed: WV+BAR)
        BARS();
        // rotate buffers
        int tmp = par; par = pn1; pn1 = pn2; pn2 = tmp;
    }
    asm volatile("s_waitcnt vmcnt(0) lgkmcnt(0)" ::: "memory");

    // ---- fused epilogue (wave = one 64-col head) -----------------------
    const int region = n0 >> 10;           // 0 qs | 1 ks | 2 qg | 3 kg | >=4 v
    const int rbase  = m0 + wm * 64 + g * 4;

    if (region <= 1) {
        ushort_t* dst = (region == 0) ? Qh : Kh;
        const int hb = ((n0 & 1023) >> 6) + wn;
        float sc = 1.0f;
        if (region == 0) sc = 0.25f / (1.0f + __expf(-gate_logit[hb]));
#pragma unroll
        for (int i = 0; i < 4; ++i)
#pragma unroll
            for (int r = 0; r < 4; ++r) {
                int row = rbase + i * 16 + r;
                int t = row & (T_ - 1), bb = row >> 11;
                size_t base = ((size_t)(bb * H_ + hb) * T_ + t) * 128;
#pragma unroll
                for (int j = 0; j < 4; ++j)
                    dst[base + j * 16 + ln16] = f2b(acc[i][j][r] * sc);
            }
    } else if (region <= 3) {
        ushort_t* dst = (region == 2) ? Qh : Kh;
        const int hb = ((n0 & 1023) >> 6) + wn;
        const float po = (float)(*pos_off);
        const float invf0 = __expf(-0.28782313665087625f * (float)ln16);
        const float invf1 = __expf(-0.28782313665087625f * (float)(16 + ln16));
        float sc = 1.0f;
        if (region == 2) sc = 0.25f * (1.0f - 1.0f / (1.0f + __expf(-gate_logit[hb])));
#pragma unroll
        for (int i = 0; i < 4; ++i)
#pragma unroll
            for (int r = 0; r < 4; ++r) {
                int row = rbase + i * 16 + r;
                int t = row & (T_ - 1), bb = row >> 11;
                size_t base = ((size_t)(bb * H_ + hb) * T_ + t) * 128;
                float s0, c0, s1, c1;
                __sincosf(((float)t + po) * invf0, &s0, &c0);
                __sincosf(((float)t + po) * invf1, &s1, &c1);
                float x1 = acc[i][0][r], x2 = acc[i][2][r];
                dst[base + 64 + ln16]      = f2b((x1 * c0 - x2 * s0) * sc);
                dst[base + 96 + ln16]      = f2b((x2 * c0 + x1 * s0) * sc);
                x1 = acc[i][1][r]; x2 = acc[i][3][r];
                dst[base + 64 + 16 + ln16] = f2b((x1 * c1 - x2 * s1) * sc);
                dst[base + 96 + 16 + ln16] = f2b((x2 * c1 + x1 * s1) * sc);
            }
    } else {
        // V region: pack 4 consecutive-t values (r=0..3) into one 8-B store
        const int hb = (n0 - 4096) >> 7;
#pragma unroll
        for (int i = 0; i < 4; ++i) {
            int row0 = rbase + i * 16;            // r = 0
            int t0 = row0 & (T_ - 1), bb = row0 >> 11;
#pragma unroll
            for (int j = 0; j < 4; ++j) {
                int cb = wn * 64 + j * 16;        // col base within 256
                int hh = hb + (cb >> 7);
                int dd = (cb & 127) + ln16;
                us4 v;
                v[0] = f2b(acc[i][j][0]); v[1] = f2b(acc[i][j][1]);
                v[2] = f2b(acc[i][j][2]); v[3] = f2b(acc[i][j][3]);
                *(us4*)&Vt[((size_t)(bb * H_ + hh) * DH_ + dd) * T_ + t0] = v;
            }
        }
    }
}

// ---------------------------------------------------------------------------
// Generic bf16 MFMA GEMM, fp32 out — used for Wo.  (counted-vmcnt
// double-buffer, round-7 version, unchanged)
// ---------------------------------------------------------------------------
#define BT_STAGE(k, buf) do { \
    gload_lds16(gA + (k),       As + (buf)*4096 + wid*1024); \
    gload_lds16(gA + (k) + K16, As + (buf)*4096 + wid*1024 + 512); \
    gload_lds16(gB + (k),       Bs + (buf)*4096 + wid*1024); \
    gload_lds16(gB + (k) + K16, Bs + (buf)*4096 + wid*1024 + 512); \
} while(0)

__global__ __launch_bounds__(256) void gemm_bt_f32(
    const ushort_t* __restrict__ A, const ushort_t* __restrict__ Bt,
    float* __restrict__ C, int M, int N, int K)
{
    __shared__ ushort_t As[2 * 128 * 32];
    __shared__ ushort_t Bs[2 * 128 * 32];

    const int tid  = threadIdx.x;
    const int wid  = tid >> 6, lane = tid & 63;
    const int ln16 = lane & 15, g = lane >> 4;
    const int wm = wid & 1, wn = wid >> 1;
    const int m0 = blockIdx.y * 128, n0 = blockIdx.x * 128;

    const int lrow = lane >> 2;
    const int lc8  = (lane & 3) * 8;
    const ushort_t* gA = A  + (size_t)(m0 + wid * 32 + lrow) * K + lc8;
    const ushort_t* gB = Bt + (size_t)(n0 + wid * 32 + lrow) * K + lc8;
    const size_t K16 = (size_t)16 * K;

    f32x4 acc[4][4];
#pragma unroll
    for (int i = 0; i < 4; ++i)
#pragma unroll
        for (int j = 0; j < 4; ++j) acc[i][j] = (f32x4){0.f, 0.f, 0.f, 0.f};

    const int nk = K >> 5;
    BT_STAGE(0, 0);
    BT_STAGE(32, 1);

#pragma unroll 1
    for (int kb = 0; kb < nk; ++kb) {
        if (kb + 1 < nk) { WV4(); } else { WV0(); }
        BARS();

        const int bufo = (kb & 1) * 4096;
        bf16x8 af[4], bfr[4];
#pragma unroll
        for (int i = 0; i < 4; ++i)
            af[i] = *(const bf16x8*)&As[bufo + (wm * 64 + i * 16 + ln16) * 32 + g * 8];
#pragma unroll
        for (int j = 0; j < 4; ++j)
            bfr[j] = *(const bf16x8*)&Bs[bufo + (wn * 64 + j * 16 + ln16) * 32 + g * 8];
        __builtin_amdgcn_s_setprio(1);
#pragma unroll
        for (int i = 0; i < 4; ++i)
#pragma unroll
            for (int j = 0; j < 4; ++j)
                acc[i][j] = __builtin_amdgcn_mfma_f32_16x16x32_bf16(
                    af[i], bfr[j], acc[i][j], 0, 0, 0);
        __builtin_amdgcn_s_setprio(0);
        WL0();
        BARS();

        if (kb + 2 < nk) BT_STAGE((size_t)(kb + 2) * 32, kb & 1);
    }

#pragma unroll
    for (int i = 0; i < 4; ++i)
#pragma unroll
        for (int j = 0; j < 4; ++j)
#pragma unroll
            for (int r = 0; r < 4; ++r) {
                int row = m0 + wm * 64 + i * 16 + g * 4 + r;
                int col = n0 + wn * 64 + j * 16 + ln16;
                C[(size_t)row * N + col] = acc[i][j][r];
            }
}

// ---------------------------------------------------------------------------
// Flash attention — counted-vmcnt pipeline + XCD-locality swizzle
// (round-7 version, unchanged).
// ---------------------------------------------------------------------------
#define P_PITCH  40

#define FA_STAGE(kt, buf) do { \
    gload_lds16(Kbase + (size_t)((kt) + kr0) * 128 + kofs0, Ks + (buf)*4096 + wid * 512); \
    gload_lds16(Kbase + (size_t)((kt) + kr1) * 128 + kofs1, Ks + (buf)*4096 + 2048 + wid * 512); \
    gload_lds16(Vbase + (size_t)vd0 * T_ + (kt) + vofs0,    Vs + (buf)*4096 + wid * 512); \
    gload_lds16(Vbase + (size_t)vd1 * T_ + (kt) + vofs1,    Vs + (buf)*4096 + 2048 + wid * 512); \
} while(0)

__global__ __launch_bounds__(256) void flash_attn(
    const ushort_t* __restrict__ Qh,
    const ushort_t* __restrict__ Kh,
    const ushort_t* __restrict__ Vt,     // [bh][128][T]
    ushort_t* __restrict__ aoh)          // [b*T+t][2048] bf16
{
    __shared__ ushort_t Ks[2 * 32 * 128];
    __shared__ ushort_t Vs[2 * 128 * 32];
    __shared__ ushort_t Pl[4 * 16 * P_PITCH];

    const int tid  = threadIdx.x;
    const int wid  = tid >> 6, lane = tid & 63;
    const int ln16 = lane & 15, g = lane >> 4;

    // XCD-locality swizzle: linear id -> (p, b, h) with lin%8 == h%8
    const int lin = blockIdx.x + (blockIdx.y << 4) + (blockIdx.z << 8);
    const int h = lin & 15;
    const int b = (lin >> 4) & 1;
    const int p = lin >> 5;              // pair index 0..15
    const int bh = b * H_ + h;

    const ushort_t* Kbase = Kh + (size_t)bh * T_ * 128;
    const ushort_t* Vbase = Vt + (size_t)bh * 128 * T_;
    ushort_t* Pw = Pl + wid * 16 * P_PITCH;

    const int sk0 = tid,      sk1 = 256 + tid;
    const int kr0 = sk0 >> 4, kc0 = sk0 & 15;
    const int kr1 = sk1 >> 4, kc1 = sk1 & 15;
    const int vd0 = sk0 >> 2, vg0 = sk0 & 3;
    const int vd1 = sk1 >> 2, vg1 = sk1 & 3;
    const int kofs0 = (kc0 ^ (kr0 & 15)) * 8, kofs1 = (kc1 ^ (kr1 & 15)) * 8;
    const int vofs0 = (vg0 ^ ((vd0 + (vd0 >> 2)) & 3)) * 8;
    const int vofs1 = (vg1 ^ ((vd1 + (vd1 >> 2)) & 3)) * 8;

    bf16x8 bones;
    {
        short o = (ln16 == 0) ? (short)0x3F80 : (short)0;
#pragma unroll
        for (int j = 0; j < 8; ++j) bones[j] = o;
    }

#pragma unroll 1
    for (int ti = 0; ti < 2; ++ti) {
        const int qt = ti ? (31 - p) : p;
        const int q0 = qt * 64;
        const int qw = q0 + wid * 16;

        bf16x8 aq[4];
        {
            const ushort_t* qrow = Qh + ((size_t)bh * T_ + qw + ln16) * 128;
#pragma unroll
            for (int c2 = 0; c2 < 4; ++c2)
                aq[c2] = *(const bf16x8*)(qrow + c2 * 32 + g * 8);
        }

        f32x4 acc[8];
#pragma unroll
        for (int i = 0; i < 8; ++i) acc[i] = (f32x4){0.f, 0.f, 0.f, 0.f};
        f32x4 acc_l = (f32x4){0.f, 0.f, 0.f, 0.f};

        const int nkb  = q0 / 32 + 2;        // block-uniform, >= 2
        const int qmax = qw + 15;

        // prologue: two tiles in flight
        FA_STAGE(0, 0);
        FA_STAGE(32, 1);

#pragma unroll 1
        for (int kb = 0; kb < nkb; ++kb) {
            const int kt = kb * 32;
            if (kb + 1 < nkb) { WV4(); } else { WV0(); }
            BARS();

            if (kt <= qmax) {
                const int kbuf = (kb & 1) * 4096;

                f32x4 s0 = (f32x4){0.f, 0.f, 0.f, 0.f};
                f32x4 s1 = (f32x4){0.f, 0.f, 0.f, 0.f};
                __builtin_amdgcn_s_setprio(1);
#pragma unroll
                for (int c2 = 0; c2 < 4; ++c2) {
                    int jk = c2 * 4 + g;
                    bf16x8 bk0 = *(const bf16x8*)&Ks[kbuf + (ln16 * 16 + (jk ^ ln16)) * 8];
                    bf16x8 bk1 = *(const bf16x8*)&Ks[kbuf + (256 + ln16 * 16 + (jk ^ ln16)) * 8];
                    s0 = __builtin_amdgcn_mfma_f32_16x16x32_bf16(aq[c2], bk0, s0, 0, 0, 0);
                    s1 = __builtin_amdgcn_mfma_f32_16x16x32_bf16(aq[c2], bk1, s1, 0, 0, 0);
                }
                __builtin_amdgcn_s_setprio(0);

                const bool diag = (kt + 31 > qw);
#pragma unroll
                for (int r2 = 0; r2 < 4; ++r2) {
                    float e0 = __expf(s0[r2] - 12.0f);
                    float e1 = __expf(s1[r2] - 12.0f);
                    if (diag) {
                        int qr = qw + g * 4 + r2;
                        e0 = (kt + ln16      > qr) ? 0.0f : e0;
                        e1 = (kt + 16 + ln16 > qr) ? 0.0f : e1;
                    }
                    int prow = g * 4 + r2;
                    Pw[prow * P_PITCH + ln16]      = f2b(e0);
                    Pw[prow * P_PITCH + 16 + ln16] = f2b(e1);
                }
                __asm__ volatile("s_waitcnt lgkmcnt(0)" ::: "memory");
                bf16x8 ap = *(const bf16x8*)&Pw[ln16 * P_PITCH + g * 8];

                __builtin_amdgcn_s_setprio(1);
#pragma unroll
                for (int cdv = 0; cdv < 8; ++cdv) {
                    int d = cdv * 16 + ln16;
                    bf16x8 bv = *(const bf16x8*)
                        &Vs[kbuf + ((d << 2) + (g ^ ((d + (d >> 2)) & 3))) * 8];
                    acc[cdv] = __builtin_amdgcn_mfma_f32_16x16x32_bf16(ap, bv, acc[cdv], 0, 0, 0);
                }
                acc_l = __builtin_amdgcn_mfma_f32_16x16x32_bf16(ap, bones, acc_l, 0, 0, 0);
                __builtin_amdgcn_s_setprio(0);
                WL0();
            }

            BARS();
            if (kb + 2 < nkb) FA_STAGE(kt + 64, kb & 1);
        }

        float invl[4];
#pragma unroll
        for (int r2 = 0; r2 < 4; ++r2)
            invl[r2] = 1.0f / __shfl(acc_l[r2], lane & 48);
#pragma unroll
        for (int cdv = 0; cdv < 8; ++cdv)
#pragma unroll
            for (int r2 = 0; r2 < 4; ++r2) {
                int qr = qw + g * 4 + r2;
                aoh[((size_t)b * T_ + qr) * D_ + h * DH_ + cdv * 16 + ln16] =
                    f2b(acc[cdv][r2] * invl[r2]);
            }
    }
}

// ---------------------------------------------------------------------------
extern "C" void kernel_launch(void* const* d_in, const int* in_sizes, int n_in,
                              void* d_out, int out_size, void* d_ws, size_t ws_size,
                              hipStream_t stream)
{
    const float* x       = (const float*)d_in[0];
    const float* Wq_sem  = (const float*)d_in[1];
    const float* Wk_sem  = (const float*)d_in[2];
    const float* Wq_geo  = (const float*)d_in[3];
    const float* Wk_geo  = (const float*)d_in[4];
    const float* Wv      = (const float*)d_in[5];
    const float* Wo      = (const float*)d_in[6];
    const float* gate    = (const float*)d_in[7];
    const int*   pos_off = (const int*)d_in[8];
    float* out = (float*)d_out;

    const int M = B_ * T_;                       // 4096
    char* ws = (char*)d_ws;
    ushort_t* xh     = (ushort_t*)(ws);                          // [4096][2048] 16MB
    ushort_t* aoh    = xh;                                       // reuse after proj
    ushort_t* Wt_all = (ushort_t*)(ws + (size_t)16 * 1048576);   // [6144][2048] 24MB
    ushort_t* WoT    = (ushort_t*)(ws + (size_t)40 * 1048576);   // [2048][2048] 8MB
    ushort_t* Qh     = (ushort_t*)(ws + (size_t)48 * 1048576);   // 16MB
    ushort_t* Kh     = (ushort_t*)(ws + (size_t)64 * 1048576);   // 16MB
    ushort_t* Vt     = (ushort_t*)(ws + (size_t)80 * 1048576);   // 16MB

    dim3 blk(256);

    convert_x<<<(M * D_) / (256 * 8), blk, 0, stream>>>(x, xh);
    transpose_all<<<dim3(32, 32, 6), blk, 0, stream>>>(
        Wq_sem, Wk_sem, Wq_geo, Wk_geo, Wv, Wo, Wt_all, WoT);

    // 128x256-tile, triple-buffered: 144 KiB dynamic LDS; 768 blocks
    hipFuncSetAttribute((const void*)gemm_proj,
                        hipFuncAttributeMaxDynamicSharedMemorySize, 147456);
    gemm_proj<<<dim3(NPROJ / 256, M / 128), dim3(512), 147456, stream>>>(
        xh, Wt_all, gate, pos_off, Qh, Kh, Vt);

    flash_attn<<<dim3(16, H_, B_), blk, 0, stream>>>(Qh, Kh, Vt, aoh);

    gemm_bt_f32<<<dim3(D_ / 128, M / 128), blk, 0, stream>>>(
        aoh, WoT, out, M, D_, D_);
}

// Round 10
// 373.493 us; speedup vs baseline: 1.0188x; 1.0188x over previous
//
#include <hip/hip_runtime.h>
#include <hip/hip_bf16.h>
#include <math.h>

#define B_ 2
#define T_ 2048
#define D_ 2048
#define H_ 16
#define DH_ 128
#define SEM_ 1024
#define GEO_ 1024
#define NPROJ 6144   // 4*1024 (q/k sem/geo) + 2048 (v)

typedef unsigned short ushort_t;
typedef short bf16x8 __attribute__((ext_vector_type(8)));
typedef float f32x4 __attribute__((ext_vector_type(4)));
typedef unsigned short us4 __attribute__((ext_vector_type(4)));
typedef unsigned short us2 __attribute__((ext_vector_type(2)));

static __device__ inline ushort_t f2b(float x) {
    __hip_bfloat16 h = __float2bfloat16(x);
    return *reinterpret_cast<ushort_t*>(&h);
}
static __device__ inline float b2f(ushort_t u) {
    union { unsigned int i; float f; } v; v.i = ((unsigned int)u) << 16; return v.f;
}
static __device__ inline void gload_lds16(const ushort_t* g, ushort_t* l) {
    __builtin_amdgcn_global_load_lds(
        (const __attribute__((address_space(1))) void*)g,
        (__attribute__((address_space(3))) void*)l, 16, 0, 0);
}

#define BARS()  { asm volatile("" ::: "memory"); __builtin_amdgcn_s_barrier(); asm volatile("" ::: "memory"); }
#define WL0()   asm volatile("s_waitcnt lgkmcnt(0)" ::: "memory")
#define WV8()   asm volatile("s_waitcnt vmcnt(8)" ::: "memory")
#define WV6()   asm volatile("s_waitcnt vmcnt(6)" ::: "memory")
#define WV4()   asm volatile("s_waitcnt vmcnt(4)" ::: "memory")
#define WV0()   asm volatile("s_waitcnt vmcnt(0)" ::: "memory")

// ---------------------------------------------------------------------------
// x fp32 -> bf16, 8 elems/thread
// ---------------------------------------------------------------------------
__global__ __launch_bounds__(256) void convert_x(
    const float* __restrict__ x, ushort_t* __restrict__ xh)
{
    size_t i = ((size_t)blockIdx.x * 256 + threadIdx.x) * 8;
    float4 a = *(const float4*)&x[i];
    float4 b = *(const float4*)&x[i + 4];
    bf16x8 o;
    o[0] = (short)f2b(a.x); o[1] = (short)f2b(a.y);
    o[2] = (short)f2b(a.z); o[3] = (short)f2b(a.w);
    o[4] = (short)f2b(b.x); o[5] = (short)f2b(b.y);
    o[6] = (short)f2b(b.z); o[7] = (short)f2b(b.w);
    *(bf16x8*)&xh[i] = o;
}

// ---------------------------------------------------------------------------
// All 6 weight transposes in one launch. z selects the weight.
// W[K=2048][N] fp32 -> dst[N][2048] bf16.  64x64 tiles, float2 reads,
// ushort2 writes.
// ---------------------------------------------------------------------------
__global__ __launch_bounds__(256) void transpose_all(
    const float* __restrict__ W0, const float* __restrict__ W1,
    const float* __restrict__ W2, const float* __restrict__ W3,
    const float* __restrict__ W4, const float* __restrict__ W5,
    ushort_t* __restrict__ Wt_all, ushort_t* __restrict__ WoT)
{
    const int z = blockIdx.z;
    const float* W;
    ushort_t* dst;
    int N;
    switch (z) {
        case 0: W = W0; dst = Wt_all;                          N = 1024; break;
        case 1: W = W1; dst = Wt_all + (size_t)1024 * 2048;    N = 1024; break;
        case 2: W = W2; dst = Wt_all + (size_t)2048 * 2048;    N = 1024; break;
        case 3: W = W3; dst = Wt_all + (size_t)3072 * 2048;    N = 1024; break;
        case 4: W = W4; dst = Wt_all + (size_t)4096 * 2048;    N = 2048; break;
        default: W = W5; dst = WoT;                            N = 2048; break;
    }
    const int n0 = blockIdx.x * 64;
    if (n0 >= N) return;
    const int k0 = blockIdx.y * 64;

    __shared__ float tile[64][66];
    const int c2 = (threadIdx.x & 31) * 2;   // n-col pair
    const int r  = threadIdx.x >> 5;         // 0..7
#pragma unroll
    for (int rr = 0; rr < 64; rr += 8) {
        float2 v = *(const float2*)&W[(size_t)(k0 + r + rr) * N + n0 + c2];
        tile[r + rr][c2]     = v.x;
        tile[r + rr][c2 + 1] = v.y;
    }
    __syncthreads();
    const int kc = (threadIdx.x & 31) * 2;   // k-col pair
#pragma unroll
    for (int rr = 0; rr < 64; rr += 8) {
        int nrow = r + rr;
        us2 o;
        o[0] = f2b(tile[kc][nrow]);
        o[1] = f2b(tile[kc + 1][nrow]);
        *(us2*)&dst[(size_t)(n0 + nrow) * 2048 + k0 + kc] = o;
    }
}

// ---------------------------------------------------------------------------
// Projection GEMM — BM=128 x BN=256, BK=64, 768 blocks, TRIPLE-buffered LDS
// (round-9 version, verified: 121.9 µs, FETCH 107 MB, 0 conflicts).
// ---------------------------------------------------------------------------
#define PLDA(par, i4, kk) \
    (*(const bf16x8*)&smA[(par)*8192 + aoff + (i4)*1024 + ((kk) ? ca1 : ca0)])
#define PLDB(par, j, kk) \
    (*(const bf16x8*)&smB[(par)*16384 + boff + (j)*1024 + ((kk) ? ca1 : ca0)])

// read one kk-slice (4 A frags + 4 B frags) into slots [off, off+4)
#define PREAD_SET(par, kk, off) \
    aF[(off)+0]=PLDA(par,0,kk); aF[(off)+1]=PLDA(par,1,kk); \
    aF[(off)+2]=PLDA(par,2,kk); aF[(off)+3]=PLDA(par,3,kk); \
    bF[(off)+0]=PLDB(par,0,kk); bF[(off)+1]=PLDB(par,1,kk); \
    bF[(off)+2]=PLDB(par,2,kk); bF[(off)+3]=PLDB(par,3,kk);

#define PMM(off) do { \
    _Pragma("unroll") \
    for (int i = 0; i < 4; ++i) { \
        acc[i][0] = __builtin_amdgcn_mfma_f32_16x16x32_bf16(aF[(off)+i], bF[(off)+0], acc[i][0], 0, 0, 0); \
        acc[i][1] = __builtin_amdgcn_mfma_f32_16x16x32_bf16(aF[(off)+i], bF[(off)+1], acc[i][1], 0, 0, 0); \
        acc[i][2] = __builtin_amdgcn_mfma_f32_16x16x32_bf16(aF[(off)+i], bF[(off)+2], acc[i][2], 0, 0, 0); \
        acc[i][3] = __builtin_amdgcn_mfma_f32_16x16x32_bf16(aF[(off)+i], bF[(off)+3], acc[i][3], 0, 0, 0); \
    } \
} while(0)

#define PSTAGE_A(kt, par) do { \
    const ushort_t* _s = gAbase + (size_t)(kt) * 64 + stgoff; \
    ushort_t* _d = smA + (par)*8192 + wid*512; \
    gload_lds16(_s, _d); \
    gload_lds16(_s + (size_t)64*2048, _d + 4096); \
} while(0)

#define PSTAGE_B(kt, par) do { \
    const ushort_t* _s = gBbase + (size_t)(kt) * 64 + stgoff; \
    ushort_t* _d = smB + (par)*16384 + wid*512; \
    gload_lds16(_s, _d); \
    gload_lds16(_s + (size_t)64*2048,  _d + 4096); \
    gload_lds16(_s + (size_t)128*2048, _d + 8192); \
    gload_lds16(_s + (size_t)192*2048, _d + 12288); \
} while(0)

__global__ __launch_bounds__(512, 2) void gemm_proj(
    const ushort_t* __restrict__ A, const ushort_t* __restrict__ Bt,
    const float* __restrict__ gate_logit, const int* __restrict__ pos_off,
    ushort_t* __restrict__ Qh, ushort_t* __restrict__ Kh,
    ushort_t* __restrict__ Vt)
{
    extern __shared__ __align__(16) ushort_t smdyn[];
    ushort_t* smA = smdyn;              // [3 buf][128][64]  48 KiB
    ushort_t* smB = smdyn + 24576;      // [3 buf][256][64]  96 KiB

    const int tid  = threadIdx.x;
    const int wid  = tid >> 6, lane = tid & 63;
    const int ln16 = lane & 15, g = lane >> 4;
    const int wm = wid & 1, wn = wid >> 1;          // wn 0..3
    const int m0 = blockIdx.y * 128, n0 = blockIdx.x * 256;

    const int srow = wid * 8 + (lane >> 3);
    const int scol = ((lane & 7) ^ (lane >> 3)) * 8;
    const size_t stgoff = (size_t)srow * 2048 + scol;
    const ushort_t* gAbase = A  + (size_t)m0 * 2048;
    const ushort_t* gBbase = Bt + (size_t)n0 * 2048;

    const int cg0 = ln16 & 7;
    const int ca0 = ((g + 0) ^ cg0) * 8;
    const int ca1 = ((g + 4) ^ cg0) * 8;
    const int aoff = wm * 4096 + ln16 * 64;
    const int boff = wn * 4096 + ln16 * 64;

    f32x4 acc[4][4];
#pragma unroll
    for (int i = 0; i < 4; ++i)
#pragma unroll
        for (int j = 0; j < 4; ++j) acc[i][j] = (f32x4){0.f, 0.f, 0.f, 0.f};
    bf16x8 aF[8], bF[8];

    // prologue: tile0 -> buf0, tile1 -> buf1 (6 loads each)
    PSTAGE_A(0, 0); PSTAGE_B(0, 0);
    PSTAGE_A(1, 1); PSTAGE_B(1, 1);
    WV6();
    BARS();
    PREAD_SET(0, 0, 0);

    int par = 0, pn1 = 1, pn2 = 2;
#pragma unroll 1
    for (int t = 0; t < 32; ++t) {
        const int t2 = t + 2;
        if (t2 < 32) { PSTAGE_A(t2, pn2); PSTAGE_B(t2, pn2); }
        BARS(); WL0();
        __builtin_amdgcn_s_setprio(1); PMM(0); __builtin_amdgcn_s_setprio(0);
        PREAD_SET(par, 1, 4);
        BARS();
        if (t < 30) { WV6(); } else { WV0(); }
        BARS(); WL0();
        __builtin_amdgcn_s_setprio(1); PMM(4); __builtin_amdgcn_s_setprio(0);
        PREAD_SET(pn1, 0, 0);
        BARS();
        int tmp = par; par = pn1; pn1 = pn2; pn2 = tmp;
    }
    asm volatile("s_waitcnt vmcnt(0) lgkmcnt(0)" ::: "memory");

    // ---- fused epilogue (wave = one 64-col head) -----------------------
    const int region = n0 >> 10;           // 0 qs | 1 ks | 2 qg | 3 kg | >=4 v
    const int rbase  = m0 + wm * 64 + g * 4;

    if (region <= 1) {
        ushort_t* dst = (region == 0) ? Qh : Kh;
        const int hb = ((n0 & 1023) >> 6) + wn;
        float sc = 1.0f;
        if (region == 0) sc = 0.25f / (1.0f + __expf(-gate_logit[hb]));
#pragma unroll
        for (int i = 0; i < 4; ++i)
#pragma unroll
            for (int r = 0; r < 4; ++r) {
                int row = rbase + i * 16 + r;
                int t = row & (T_ - 1), bb = row >> 11;
                size_t base = ((size_t)(bb * H_ + hb) * T_ + t) * 128;
#pragma unroll
                for (int j = 0; j < 4; ++j)
                    dst[base + j * 16 + ln16] = f2b(acc[i][j][r] * sc);
            }
    } else if (region <= 3) {
        ushort_t* dst = (region == 2) ? Qh : Kh;
        const int hb = ((n0 & 1023) >> 6) + wn;
        const float po = (float)(*pos_off);
        const float invf0 = __expf(-0.28782313665087625f * (float)ln16);
        const float invf1 = __expf(-0.28782313665087625f * (float)(16 + ln16));
        float sc = 1.0f;
        if (region == 2) sc = 0.25f * (1.0f - 1.0f / (1.0f + __expf(-gate_logit[hb])));
#pragma unroll
        for (int i = 0; i < 4; ++i)
#pragma unroll
            for (int r = 0; r < 4; ++r) {
                int row = rbase + i * 16 + r;
                int t = row & (T_ - 1), bb = row >> 11;
                size_t base = ((size_t)(bb * H_ + hb) * T_ + t) * 128;
                float s0, c0, s1, c1;
                __sincosf(((float)t + po) * invf0, &s0, &c0);
                __sincosf(((float)t + po) * invf1, &s1, &c1);
                float x1 = acc[i][0][r], x2 = acc[i][2][r];
                dst[base + 64 + ln16]      = f2b((x1 * c0 - x2 * s0) * sc);
                dst[base + 96 + ln16]      = f2b((x2 * c0 + x1 * s0) * sc);
                x1 = acc[i][1][r]; x2 = acc[i][3][r];
                dst[base + 64 + 16 + ln16] = f2b((x1 * c1 - x2 * s1) * sc);
                dst[base + 96 + 16 + ln16] = f2b((x2 * c1 + x1 * s1) * sc);
            }
    } else {
        const int hb = (n0 - 4096) >> 7;
#pragma unroll
        for (int i = 0; i < 4; ++i) {
            int row0 = rbase + i * 16;            // r = 0
            int t0 = row0 & (T_ - 1), bb = row0 >> 11;
#pragma unroll
            for (int j = 0; j < 4; ++j) {
                int cb = wn * 64 + j * 16;        // col base within 256
                int hh = hb + (cb >> 7);
                int dd = (cb & 127) + ln16;
                us4 v;
                v[0] = f2b(acc[i][j][0]); v[1] = f2b(acc[i][j][1]);
                v[2] = f2b(acc[i][j][2]); v[3] = f2b(acc[i][j][3]);
                *(us4*)&Vt[((size_t)(bb * H_ + hh) * DH_ + dd) * T_ + t0] = v;
            }
        }
    }
}

// ---------------------------------------------------------------------------
// Generic bf16 MFMA GEMM, fp32 out — used for Wo.  (counted-vmcnt
// double-buffer, round-7 version, unchanged)
// ---------------------------------------------------------------------------
#define BT_STAGE(k, buf) do { \
    gload_lds16(gA + (k),       As + (buf)*4096 + wid*1024); \
    gload_lds16(gA + (k) + K16, As + (buf)*4096 + wid*1024 + 512); \
    gload_lds16(gB + (k),       Bs + (buf)*4096 + wid*1024); \
    gload_lds16(gB + (k) + K16, Bs + (buf)*4096 + wid*1024 + 512); \
} while(0)

__global__ __launch_bounds__(256) void gemm_bt_f32(
    const ushort_t* __restrict__ A, const ushort_t* __restrict__ Bt,
    float* __restrict__ C, int M, int N, int K)
{
    __shared__ ushort_t As[2 * 128 * 32];
    __shared__ ushort_t Bs[2 * 128 * 32];

    const int tid  = threadIdx.x;
    const int wid  = tid >> 6, lane = tid & 63;
    const int ln16 = lane & 15, g = lane >> 4;
    const int wm = wid & 1, wn = wid >> 1;
    const int m0 = blockIdx.y * 128, n0 = blockIdx.x * 128;

    const int lrow = lane >> 2;
    const int lc8  = (lane & 3) * 8;
    const ushort_t* gA = A  + (size_t)(m0 + wid * 32 + lrow) * K + lc8;
    const ushort_t* gB = Bt + (size_t)(n0 + wid * 32 + lrow) * K + lc8;
    const size_t K16 = (size_t)16 * K;

    f32x4 acc[4][4];
#pragma unroll
    for (int i = 0; i < 4; ++i)
#pragma unroll
        for (int j = 0; j < 4; ++j) acc[i][j] = (f32x4){0.f, 0.f, 0.f, 0.f};

    const int nk = K >> 5;
    BT_STAGE(0, 0);
    BT_STAGE(32, 1);

#pragma unroll 1
    for (int kb = 0; kb < nk; ++kb) {
        if (kb + 1 < nk) { WV4(); } else { WV0(); }
        BARS();

        const int bufo = (kb & 1) * 4096;
        bf16x8 af[4], bfr[4];
#pragma unroll
        for (int i = 0; i < 4; ++i)
            af[i] = *(const bf16x8*)&As[bufo + (wm * 64 + i * 16 + ln16) * 32 + g * 8];
#pragma unroll
        for (int j = 0; j < 4; ++j)
            bfr[j] = *(const bf16x8*)&Bs[bufo + (wn * 64 + j * 16 + ln16) * 32 + g * 8];
        __builtin_amdgcn_s_setprio(1);
#pragma unroll
        for (int i = 0; i < 4; ++i)
#pragma unroll
            for (int j = 0; j < 4; ++j)
                acc[i][j] = __builtin_amdgcn_mfma_f32_16x16x32_bf16(
                    af[i], bfr[j], acc[i][j], 0, 0, 0);
        __builtin_amdgcn_s_setprio(0);
        WL0();
        BARS();

        if (kb + 2 < nk) BT_STAGE((size_t)(kb + 2) * 32, kb & 1);
    }

#pragma unroll
    for (int i = 0; i < 4; ++i)
#pragma unroll
        for (int j = 0; j < 4; ++j)
#pragma unroll
            for (int r = 0; r < 4; ++r) {
                int row = m0 + wm * 64 + i * 16 + g * 4 + r;
                int col = n0 + wn * 64 + j * 16 + ln16;
                C[(size_t)row * N + col] = acc[i][j][r];
            }
}

// ---------------------------------------------------------------------------
// Flash attention — round-10: KVBLK=64 (halves iteration count and per-K
// barrier/waitcnt overhead).  Each 64-tile = two 32-wide stage chunks
// (identical swizzle formulas) in adjacent 8-KB halves.  vmcnt ledger:
// 8 loads/stage, 2 stages in flight -> WV8 in-loop, WV0 only on the last
// tile.  QK^T = 4 s-groups; PV consumes ap0 (k 0..31) then ap1 (32..63)
// per accumulator — accumulation order identical to two 32-iterations
// (bit-identical numerics).  XCD-locality swizzle kept.  LDS 73 KiB
// (2 blocks/CU, same residency as before: grid 512 = 2/CU).
// ---------------------------------------------------------------------------
#define P_PITCH  72

#define FA_STAGE32(kt, buf, half) do { \
    gload_lds16(Kbase + (size_t)((kt) + kr0) * 128 + kofs0, Ks + (buf)*8192 + (half)*4096 + wid * 512); \
    gload_lds16(Kbase + (size_t)((kt) + kr1) * 128 + kofs1, Ks + (buf)*8192 + (half)*4096 + 2048 + wid * 512); \
    gload_lds16(Vbase + (size_t)vd0 * T_ + (kt) + vofs0,    Vs + (buf)*8192 + (half)*4096 + wid * 512); \
    gload_lds16(Vbase + (size_t)vd1 * T_ + (kt) + vofs1,    Vs + (buf)*8192 + (half)*4096 + 2048 + wid * 512); \
} while(0)

#define FA_STAGE64(kt, buf) do { FA_STAGE32((kt), buf, 0); FA_STAGE32((kt) + 32, buf, 1); } while(0)

__global__ __launch_bounds__(256) void flash_attn(
    const ushort_t* __restrict__ Qh,
    const ushort_t* __restrict__ Kh,
    const ushort_t* __restrict__ Vt,     // [bh][128][T]
    ushort_t* __restrict__ aoh)          // [b*T+t][2048] bf16
{
    __shared__ ushort_t Ks[2 * 2 * 32 * 128];     // 32 KiB
    __shared__ ushort_t Vs[2 * 2 * 128 * 32];     // 32 KiB
    __shared__ ushort_t Pl[4 * 16 * P_PITCH];     // 9 KiB

    const int tid  = threadIdx.x;
    const int wid  = tid >> 6, lane = tid & 63;
    const int ln16 = lane & 15, g = lane >> 4;

    // XCD-locality swizzle: linear id -> (p, b, h) with lin%8 == h%8
    const int lin = blockIdx.x + (blockIdx.y << 4) + (blockIdx.z << 8);
    const int h = lin & 15;
    const int b = (lin >> 4) & 1;
    const int p = lin >> 5;              // pair index 0..15
    const int bh = b * H_ + h;

    const ushort_t* Kbase = Kh + (size_t)bh * T_ * 128;
    const ushort_t* Vbase = Vt + (size_t)bh * 128 * T_;
    ushort_t* Pw = Pl + wid * 16 * P_PITCH;

    const int sk0 = tid,      sk1 = 256 + tid;
    const int kr0 = sk0 >> 4, kc0 = sk0 & 15;
    const int kr1 = sk1 >> 4, kc1 = sk1 & 15;
    const int vd0 = sk0 >> 2, vg0 = sk0 & 3;
    const int vd1 = sk1 >> 2, vg1 = sk1 & 3;
    const int kofs0 = (kc0 ^ (kr0 & 15)) * 8, kofs1 = (kc1 ^ (kr1 & 15)) * 8;
    const int vofs0 = (vg0 ^ ((vd0 + (vd0 >> 2)) & 3)) * 8;
    const int vofs1 = (vg1 ^ ((vd1 + (vd1 >> 2)) & 3)) * 8;

    bf16x8 bones;
    {
        short o = (ln16 == 0) ? (short)0x3F80 : (short)0;
#pragma unroll
        for (int j = 0; j < 8; ++j) bones[j] = o;
    }

#pragma unroll 1
    for (int ti = 0; ti < 2; ++ti) {
        const int qt = ti ? (31 - p) : p;
        const int q0 = qt * 64;
        const int qw = q0 + wid * 16;

        bf16x8 aq[4];
        {
            const ushort_t* qrow = Qh + ((size_t)bh * T_ + qw + ln16) * 128;
#pragma unroll
            for (int c2 = 0; c2 < 4; ++c2)
                aq[c2] = *(const bf16x8*)(qrow + c2 * 32 + g * 8);
        }

        f32x4 acc[8];
#pragma unroll
        for (int i = 0; i < 8; ++i) acc[i] = (f32x4){0.f, 0.f, 0.f, 0.f};
        f32x4 acc_l = (f32x4){0.f, 0.f, 0.f, 0.f};

        const int nkb  = qt + 1;             // 64-wide tiles, block-uniform
        const int qmax = qw + 15;

        // prologue: up to two tiles in flight
        FA_STAGE64(0, 0);
        if (nkb > 1) FA_STAGE64(64, 1);

#pragma unroll 1
        for (int kb = 0; kb < nkb; ++kb) {
            const int kt = kb * 64;
            if (kb + 1 < nkb) { WV8(); } else { WV0(); }
            BARS();

            if (kt <= qmax) {
                const int kbuf = (kb & 1) * 8192;

                f32x4 sg[4];
#pragma unroll
                for (int s = 0; s < 4; ++s) sg[s] = (f32x4){0.f, 0.f, 0.f, 0.f};
                __builtin_amdgcn_s_setprio(1);
#pragma unroll
                for (int c2 = 0; c2 < 4; ++c2) {
                    int jk = c2 * 4 + g;
                    int so = (ln16 * 16 + (jk ^ ln16)) * 8;
                    bf16x8 bkA = *(const bf16x8*)&Ks[kbuf + so];
                    bf16x8 bkB = *(const bf16x8*)&Ks[kbuf + 2048 + so];
                    bf16x8 bkC = *(const bf16x8*)&Ks[kbuf + 4096 + so];
                    bf16x8 bkD = *(const bf16x8*)&Ks[kbuf + 6144 + so];
                    sg[0] = __builtin_amdgcn_mfma_f32_16x16x32_bf16(aq[c2], bkA, sg[0], 0, 0, 0);
                    sg[1] = __builtin_amdgcn_mfma_f32_16x16x32_bf16(aq[c2], bkB, sg[1], 0, 0, 0);
                    sg[2] = __builtin_amdgcn_mfma_f32_16x16x32_bf16(aq[c2], bkC, sg[2], 0, 0, 0);
                    sg[3] = __builtin_amdgcn_mfma_f32_16x16x32_bf16(aq[c2], bkD, sg[3], 0, 0, 0);
                }
                __builtin_amdgcn_s_setprio(0);

                const bool diag = (kt + 63 > qw);
#pragma unroll
                for (int r2 = 0; r2 < 4; ++r2) {
                    float e0 = __expf(sg[0][r2] - 12.0f);
                    float e1 = __expf(sg[1][r2] - 12.0f);
                    float e2 = __expf(sg[2][r2] - 12.0f);
                    float e3 = __expf(sg[3][r2] - 12.0f);
                    if (diag) {
                        int qr = qw + g * 4 + r2;
                        e0 = (kt + ln16      > qr) ? 0.0f : e0;
                        e1 = (kt + 16 + ln16 > qr) ? 0.0f : e1;
                        e2 = (kt + 32 + ln16 > qr) ? 0.0f : e2;
                        e3 = (kt + 48 + ln16 > qr) ? 0.0f : e3;
                    }
                    int prow = g * 4 + r2;
                    Pw[prow * P_PITCH + ln16]      = f2b(e0);
                    Pw[prow * P_PITCH + 16 + ln16] = f2b(e1);
                    Pw[prow * P_PITCH + 32 + ln16] = f2b(e2);
                    Pw[prow * P_PITCH + 48 + ln16] = f2b(e3);
                }
                __asm__ volatile("s_waitcnt lgkmcnt(0)" ::: "memory");
                bf16x8 ap0 = *(const bf16x8*)&Pw[ln16 * P_PITCH + g * 8];
                bf16x8 ap1 = *(const bf16x8*)&Pw[ln16 * P_PITCH + 32 + g * 8];

                __builtin_amdgcn_s_setprio(1);
#pragma unroll
                for (int cdv = 0; cdv < 8; ++cdv) {
                    int d = cdv * 16 + ln16;
                    int vo = ((d << 2) + (g ^ ((d + (d >> 2)) & 3))) * 8;
                    bf16x8 bv0 = *(const bf16x8*)&Vs[kbuf + vo];
                    bf16x8 bv1 = *(const bf16x8*)&Vs[kbuf + 4096 + vo];
                    acc[cdv] = __builtin_amdgcn_mfma_f32_16x16x32_bf16(ap0, bv0, acc[cdv], 0, 0, 0);
                    acc[cdv] = __builtin_amdgcn_mfma_f32_16x16x32_bf16(ap1, bv1, acc[cdv], 0, 0, 0);
                }
                acc_l = __builtin_amdgcn_mfma_f32_16x16x32_bf16(ap0, bones, acc_l, 0, 0, 0);
                acc_l = __builtin_amdgcn_mfma_f32_16x16x32_bf16(ap1, bones, acc_l, 0, 0, 0);
                __builtin_amdgcn_s_setprio(0);
                WL0();
            }

            BARS();
            if (kb + 2 < nkb) FA_STAGE64(kt + 128, kb & 1);
        }

        float invl[4];
#pragma unroll
        for (int r2 = 0; r2 < 4; ++r2)
            invl[r2] = 1.0f / __shfl(acc_l[r2], lane & 48);
#pragma unroll
        for (int cdv = 0; cdv < 8; ++cdv)
#pragma unroll
            for (int r2 = 0; r2 < 4; ++r2) {
                int qr = qw + g * 4 + r2;
                aoh[((size_t)b * T_ + qr) * D_ + h * DH_ + cdv * 16 + ln16] =
                    f2b(acc[cdv][r2] * invl[r2]);
            }
    }
}

// ---------------------------------------------------------------------------
extern "C" void kernel_launch(void* const* d_in, const int* in_sizes, int n_in,
                              void* d_out, int out_size, void* d_ws, size_t ws_size,
                              hipStream_t stream)
{
    const float* x       = (const float*)d_in[0];
    const float* Wq_sem  = (const float*)d_in[1];
    const float* Wk_sem  = (const float*)d_in[2];
    const float* Wq_geo  = (const float*)d_in[3];
    const float* Wk_geo  = (const float*)d_in[4];
    const float* Wv      = (const float*)d_in[5];
    const float* Wo      = (const float*)d_in[6];
    const float* gate    = (const float*)d_in[7];
    const int*   pos_off = (const int*)d_in[8];
    float* out = (float*)d_out;

    const int M = B_ * T_;                       // 4096
    char* ws = (char*)d_ws;
    ushort_t* xh     = (ushort_t*)(ws);                          // [4096][2048] 16MB
    ushort_t* aoh    = xh;                                       // reuse after proj
    ushort_t* Wt_all = (ushort_t*)(ws + (size_t)16 * 1048576);   // [6144][2048] 24MB
    ushort_t* WoT    = (ushort_t*)(ws + (size_t)40 * 1048576);   // [2048][2048] 8MB
    ushort_t* Qh     = (ushort_t*)(ws + (size_t)48 * 1048576);   // 16MB
    ushort_t* Kh     = (ushort_t*)(ws + (size_t)64 * 1048576);   // 16MB
    ushort_t* Vt     = (ushort_t*)(ws + (size_t)80 * 1048576);   // 16MB

    dim3 blk(256);

    convert_x<<<(M * D_) / (256 * 8), blk, 0, stream>>>(x, xh);
    transpose_all<<<dim3(32, 32, 6), blk, 0, stream>>>(
        Wq_sem, Wk_sem, Wq_geo, Wk_geo, Wv, Wo, Wt_all, WoT);

    // 128x256-tile, triple-buffered: 144 KiB dynamic LDS; 768 blocks
    hipFuncSetAttribute((const void*)gemm_proj,
                        hipFuncAttributeMaxDynamicSharedMemorySize, 147456);
    gemm_proj<<<dim3(NPROJ / 256, M / 128), dim3(512), 147456, stream>>>(
        xh, Wt_all, gate, pos_off, Qh, Kh, Vt);

    flash_attn<<<dim3(16, H_, B_), blk, 0, stream>>>(Qh, Kh, Vt, aoh);

    gemm_bt_f32<<<dim3(D_ / 128, M / 128), blk, 0, stream>>>(
        aoh, WoT, out, M, D_, D_);
}